// Round 6
// baseline (158.847 us; speedup 1.0000x reference)
//
#include <hip/hip_runtime.h>
#include <hip/hip_bf16.h>
#include <math.h>

#define EMBED 768
#define NTOK  4096
#define NB    4
#define ROWS  16384          // 4 * 4096
#define CN    192            // Q(64)|K(64)|V(64)

typedef __attribute__((ext_vector_type(8)))  short bf16x8;           // 8 bf16 = 4 VGPR
typedef __attribute__((ext_vector_type(8)))  unsigned short u16x8;   // store vector
typedef __attribute__((ext_vector_type(16))) float f32x16;           // 32x32 MFMA acc

// Split fp32 into h + l bf16 (RNE both, tie-parity exact): used in wprep.
__device__ inline void split2(float f, short& h, short& l) {
  union { float f; unsigned u; } a; a.f = f;
  unsigned r = (a.u + 0x7FFFu + ((a.u >> 16) & 1u)) & 0xFFFF0000u;
  h = (short)(r >> 16);
  union { unsigned u; float f; } hf; hf.u = r;
  union { float f; unsigned u; } b; b.f = f - hf.f;
  l = (short)((b.u + 0x7FFFu + ((b.u >> 16) & 1u)) >> 16);
}

// ---------------------------------------------------------------------------
// W prep + C/Vsum zeroing.
// Wt[ks][plane][q][n][j] bf16: elem = ks*12288 + p*6144 + q*1536 + n*8 + j,
//   k = ks*32 + q*8 + j, n in [0,192). A 192-k quarter (6 ks-groups) is a
//   verbatim 147456-B slice -> LDS-stageable with zero reshuffle.
// Blocks 0..71: transpose one (mat, ks). ALL 256 blocks: zero a slice of C.
// ---------------------------------------------------------------------------
__global__ __launch_bounds__(256) void wprep(const float* __restrict__ Wq,
                                             const float* __restrict__ Wk,
                                             const float* __restrict__ Wv,
                                             unsigned short* __restrict__ Wt,
                                             float* __restrict__ Vsum,
                                             float* __restrict__ C) {
  const int b = blockIdx.x;
  const int t = threadIdx.x;

  if (b < 72) {
    __shared__ float tile[32 * 64];   // W[ks*32 .. +32][0..64]
    const int mat = b / 24;           // 0=Wq 1=Wk 2=Wv
    const int ks  = b - mat * 24;
    const float* W = (mat == 0) ? Wq : (mat == 1) ? Wk : Wv;

    const float4* src = (const float4*)(W + ks * 2048);
    ((float4*)tile)[t]       = src[t];
    ((float4*)tile)[t + 256] = src[t + 256];
    __syncthreads();

    const int q    = t >> 6;          // k-oct 0..3
    const int nloc = t & 63;          // 0..63 within this matrix
    u16x8 hv, lv;
#pragma unroll
    for (int j = 0; j < 8; ++j) {
      short h, l;
      split2(tile[(q * 8 + j) * 64 + nloc], h, l);
      hv[j] = (unsigned short)h;
      lv[j] = (unsigned short)l;
    }
    const size_t base = (size_t)ks * 12288 + (size_t)q * 1536 + (size_t)(mat * 64 + nloc) * 8;
    *(u16x8*)(Wt + base)        = hv;
    *(u16x8*)(Wt + base + 6144) = lv;
  }

  // zero C (16384*192 fp32 = 786432 float4) across all 256 blocks
  float4 z; z.x = 0.f; z.y = 0.f; z.z = 0.f; z.w = 0.f;
  float4* C4 = (float4*)C;
  for (int i = b * 256 + t; i < 786432; i += 65536) C4[i] = z;

  if (b == 0) Vsum[t] = 0.f;   // t < 256 = NB*64
}

// ---------------------------------------------------------------------------
// MFMA GEMM, K-split x4: C[16384][192] += x @ W (quarter-k) via 32x32x16
// split-bf16 (3 passes). 256 blocks x 1024 threads (16 waves: 8m x 2n),
// block tile 256 rows x 192 cols x 192 k. Each block stages its 144-KiB
// B-quarter into LDS ONCE (global_load_lds, single barrier), then free-runs:
// per wave per k16-step: 2 A-loads (global) + 6 ds_read_b128 + 9 MFMA.
// B never touches the vector path in the loop. Merge via device-scope
// atomicAdd into zeroed C; bias + Vsum handled by kq==0 blocks.
// Mapping: kq = bid>>6, mc = bid&63 -> the 4 kq-blocks of an m-chunk share
// an XCD (x rows L2-local); every x byte is read exactly once globally.
// ---------------------------------------------------------------------------
__device__ inline void gload_lds16(const unsigned short* g, unsigned short* l) {
  __builtin_amdgcn_global_load_lds(
      (const __attribute__((address_space(1))) unsigned int*)(g),
      (__attribute__((address_space(3))) unsigned int*)(l),
      16, 0, 0);
}

// HW RNE split: f = h + l, both planes RNE.
__device__ inline void splitHW(float f, short& h, short& l) {
  __hip_bfloat16 hb = __float2bfloat16(f);
  float hf = __bfloat162float(hb);
  __hip_bfloat16 lb = __float2bfloat16(f - hf);
  h = __builtin_bit_cast(short, hb);
  l = __builtin_bit_cast(short, lb);
}

__device__ inline void cvt8hw(const float4 f0, const float4 f1, bf16x8& h, bf16x8& l) {
  short hh, ll;
  splitHW(f0.x, hh, ll); h[0] = hh; l[0] = ll;
  splitHW(f0.y, hh, ll); h[1] = hh; l[1] = ll;
  splitHW(f0.z, hh, ll); h[2] = hh; l[2] = ll;
  splitHW(f0.w, hh, ll); h[3] = hh; l[3] = ll;
  splitHW(f1.x, hh, ll); h[4] = hh; l[4] = ll;
  splitHW(f1.y, hh, ll); h[5] = hh; l[5] = ll;
  splitHW(f1.z, hh, ll); h[6] = hh; l[6] = ll;
  splitHW(f1.w, hh, ll); h[7] = hh; l[7] = ll;
}

#define MFMA32(A, B, ACC) \
  ACC = __builtin_amdgcn_mfma_f32_32x32x16_bf16(A, B, ACC, 0, 0, 0)

__global__ __launch_bounds__(1024, 2) void qkv_mfma(const float* __restrict__ x,
                                                    const unsigned short* __restrict__ Wtu,
                                                    const float* __restrict__ bq,
                                                    const float* __restrict__ bk,
                                                    const float* __restrict__ bv,
                                                    float* __restrict__ C,
                                                    float* __restrict__ Vsum) {
  extern __shared__ unsigned short lds[];   // 73728 shorts = 147456 B

  const int tid  = threadIdx.x;
  const int lane = tid & 63;
  const int wid  = tid >> 6;          // 0..15
  const int wm   = wid >> 1;          // 0..7 : 32-row slice
  const int nb   = (wid & 1) * 96;    // n-half base
  const int l31  = lane & 31;
  const int l5   = lane >> 5;         // k-oct select within step
  const int bid  = blockIdx.x;
  const int kq   = bid >> 6;          // k-quarter 0..3
  const int mc   = bid & 63;          // m-chunk (256 rows)
  const int r0w  = mc * 256 + wm * 32;

  // ---- stage this block's B-quarter into LDS (linear, once) ----
  {
    const unsigned short* g = Wtu + (size_t)kq * 73728 + tid * 8;
    unsigned short* l = lds + tid * 8;
#pragma unroll
    for (int i = 0; i < 9; ++i)
      gload_lds16(g + i * 8192, l + i * 8192);
  }

  f32x16 acc0 = {}, acc1 = {}, acc2 = {};

  const float* xa = x + (size_t)(r0w + l31) * EMBED + kq * 192 + l5 * 8;
  float4 a0 = *(const float4*)xa;
  float4 a1 = *(const float4*)(xa + 4);

  __syncthreads();   // staging (and A t=0) drained

  // B frag base in LDS (shorts); per-step advance +3072 / +9216 alternating.
  const unsigned short* lb = lds + nb * 8 + l5 * 1536 + l31 * 8;

  for (int t = 0; t < 12; ++t) {
    float4 n0, n1;
    if (t < 11) {                      // prefetch next A
      n0 = *(const float4*)(xa + 16);
      n1 = *(const float4*)(xa + 20);
    }
    bf16x8 ah, al;
    cvt8hw(a0, a1, ah, al);
    bf16x8 b0h = *(const bf16x8*)(lb);
    bf16x8 b0l = *(const bf16x8*)(lb + 6144);
    bf16x8 b1h = *(const bf16x8*)(lb + 256);
    bf16x8 b1l = *(const bf16x8*)(lb + 6400);
    bf16x8 b2h = *(const bf16x8*)(lb + 512);
    bf16x8 b2l = *(const bf16x8*)(lb + 6656);
    MFMA32(ah, b0h, acc0); MFMA32(ah, b1h, acc1); MFMA32(ah, b2h, acc2);
    MFMA32(ah, b0l, acc0); MFMA32(ah, b1l, acc1); MFMA32(ah, b2l, acc2);
    MFMA32(al, b0h, acc0); MFMA32(al, b1h, acc1); MFMA32(al, b2h, acc2);
    xa += 16;
    lb += (t & 1) ? 9216 : 3072;
    a0 = n0; a1 = n1;
  }

  // ---- epilogue: atomic merge (+bias from kq==0). C/D: col=lane&31,
  // row = (reg&3) + 8*(reg>>2) + 4*(lane>>5). ----
#define EPI32(CT, ACC) do {                                                  \
    const int col = nb + (CT) * 32 + l31;                                    \
    float bias = 0.f;                                                        \
    if (kq == 0)                                                             \
      bias = (col < 64) ? bq[col] : (col < 128) ? bk[col - 64] : bv[col - 128]; \
    _Pragma("unroll")                                                        \
    for (int reg = 0; reg < 16; ++reg) {                                     \
      const int row = r0w + (reg & 3) + 8 * (reg >> 2) + 4 * l5;             \
      atomicAdd(&C[(size_t)row * CN + col], ACC[reg] + bias);                \
    }                                                                        \
  } while (0)

  EPI32(0, acc0); EPI32(1, acc1); EPI32(2, acc2);

  // ---- fused Vsum partials: V cols (>=128) are nb==96, CT 1..2. Each lane
  // sums its 16 rows, partner lane (^32) the other 16; kq==0 adds 32*bias. ----
#define VSUM32(CT, ACC) do {                                                 \
    const int col = nb + (CT) * 32 + l31;                                    \
    if (col >= 128) {                                                        \
      float s = 0.f;                                                         \
      _Pragma("unroll")                                                      \
      for (int reg = 0; reg < 16; ++reg) s += ACC[reg];                      \
      s += __shfl_xor(s, 32, 64);                                            \
      if (kq == 0) s += 32.f * bv[col - 128];                                \
      if (lane < 32) atomicAdd(&Vsum[(r0w >> 12) * 64 + (col - 128)], s);    \
    }                                                                        \
  } while (0)

  VSUM32(1, acc1); VSUM32(2, acc2);
}

// ---------------------------------------------------------------------------
// Per-row scores + softmax-with-zero-background + V combine (faithful quirk).
// ---------------------------------------------------------------------------
__global__ __launch_bounds__(256) void attn_kernel(const float* __restrict__ C,
                                                   const float* __restrict__ Vsum,
                                                   float* __restrict__ out) {
  const int t    = threadIdx.x;
  const int lane = t & 63;
  const int wave = t >> 6;
  const int r = blockIdx.x * 4 + wave;
  const int b = r >> 12;
  const int i = r & (NTOK - 1);

  const float q  = C[(size_t)r * CN + lane];
  const float kc = C[(size_t)r * CN + 64 + lane];
  float km = 0.f, kp = 0.f;
  if (i > 0)        km = C[(size_t)(r - 1) * CN + 64 + lane];
  if (i < NTOK - 1) kp = C[(size_t)(r + 1) * CN + 64 + lane];

  float p0 = q * km, p1 = q * kc, p2 = q * kp;
#pragma unroll
  for (int off = 32; off > 0; off >>= 1) {
    p0 += __shfl_xor(p0, off, 64);
    p1 += __shfl_xor(p1, off, 64);
    p2 += __shfl_xor(p2, off, 64);
  }

  const float s0 = (i > 0) ? p0 : 0.f;
  const float s1 = p1;
  const float s2 = (i < NTOK - 1) ? p2 : 0.f;
  const float m  = fmaxf(fmaxf(s0, s1), fmaxf(s2, 0.f));
  const float e0 = expf(s0 - m);
  const float e1 = expf(s1 - m);
  const float e2 = expf(s2 - m);
  const float ez = expf(-m);
  const float Z  = e0 + e1 + e2 + (float)(NTOK - 3) * ez;

  const size_t vb = ((size_t)b * NTOK) * CN + 128;
  const float v0 = C[vb + lane];
  const float v1 = C[vb + CN + lane];
  const float v2 = C[vb + 2 * (size_t)CN + lane];
  const float vs = Vsum[b * 64 + lane];

  out[(size_t)r * 64 + lane] =
      (e0 * v0 + e1 * v1 + e2 * v2 + ez * (vs - v0 - v1 - v2)) / Z;
}

// ---------------------------------------------------------------------------
extern "C" void kernel_launch(void* const* d_in, const int* in_sizes, int n_in,
                              void* d_out, int out_size, void* d_ws, size_t ws_size,
                              hipStream_t stream) {
  const float* x  = (const float*)d_in[0];
  const float* Wq = (const float*)d_in[1];
  const float* bq = (const float*)d_in[2];
  const float* Wk = (const float*)d_in[3];
  const float* bk = (const float*)d_in[4];
  const float* Wv = (const float*)d_in[5];
  const float* bv = (const float*)d_in[6];
  float* out = (float*)d_out;

  float* C    = (float*)d_ws;                              // 16384 x 192 fp32 (12 MiB)
  float* Vsum = C + (size_t)ROWS * CN;                     // 4 x 64
  unsigned short* Wt = (unsigned short*)(Vsum + NB * 64);  // 24 x 2 x 192 x 32 bf16 (576 KiB)

  wprep<<<256, 256, 0, stream>>>(Wq, Wk, Wv, Wt, Vsum, C);
  qkv_mfma<<<256, 1024, 147456, stream>>>(x, Wt, bq, bk, bv, C, Vsum);
  attn_kernel<<<ROWS / 4, 256, 0, stream>>>(C, Vsum, out);
}

// Round 8
// 127.511 us; speedup vs baseline: 1.2457x; 1.2457x over previous
//
#include <hip/hip_runtime.h>
#include <hip/hip_bf16.h>
#include <math.h>

#define EMBED 768
#define NTOK  4096
#define NB    4
#define ROWS  16384          // 4 * 4096
#define CN    192            // Q(64)|K(64)|V(64)

typedef __attribute__((ext_vector_type(8))) short bf16x8;          // 8 bf16 = 4 VGPR
typedef __attribute__((ext_vector_type(8))) unsigned short u16x8;  // store vector
typedef __attribute__((ext_vector_type(4))) float f32x4;           // MFMA acc

struct hl16 { unsigned short h, l; };

// RNE split f = h + l (both planes RNE, tie-parity exact): W path.
__device__ inline hl16 split2(float f) {
  hl16 r;
  union { float f; unsigned u; } a; a.f = f;
  unsigned rr = (a.u + 0x7FFFu + ((a.u >> 16) & 1u)) & 0xFFFF0000u;
  r.h = (unsigned short)(rr >> 16);
  union { unsigned u; float f; } hf; hf.u = rr;
  union { float f; unsigned u; } b; b.f = f - hf.f;
  r.l = (unsigned short)((b.u + 0x7FFFu + ((b.u >> 16) & 1u)) >> 16);
  return r;
}

// HW RNE split (v_cvt path): X path — same rounding as rounds 2-6.
__device__ inline hl16 splitHW(float f) {
  hl16 r;
  __hip_bfloat16 hb = __float2bfloat16(f);
  float hf = __bfloat162float(hb);
  __hip_bfloat16 lb = __float2bfloat16(f - hf);
  r.h = __builtin_bit_cast(unsigned short, hb);
  r.l = __builtin_bit_cast(unsigned short, lb);
  return r;
}

// ---------------------------------------------------------------------------
// prep: (a) Xt — x pre-split to bf16 h/l planes in MFMA-A-fragment order:
//   Xt[(mt*24 + ks)*1024 + p*512 + lane*8 + j], lane = q*16 + ml,
//   element = x[row = mt*16 + ml][k = ks*32 + q*8 + j].
//   => a wave's A-fragment load in qkv is ONE contiguous 1 KiB read.
// (b) Wt — W split to h/l planes, n-block-major so qkv's 144-KiB LDS stage
//   is a verbatim linear copy:
//   Wt[nqb*73728 + ks*3072 + p*1536 + q*384 + col*8 + j], n = nqb*48 + col.
// (c) zeroes Vsum.
// Blocks [0,6144): Xt (4 units of 64 lanes each). Blocks [6144,6216): Wt.
// ---------------------------------------------------------------------------
__global__ __launch_bounds__(256) void prep(const float* __restrict__ x,
                                            const float* __restrict__ Wq,
                                            const float* __restrict__ Wk,
                                            const float* __restrict__ Wv,
                                            unsigned short* __restrict__ Wt,
                                            unsigned short* __restrict__ Xt,
                                            float* __restrict__ Vsum) {
  __shared__ float tile[32 * 64];
  const int bid = blockIdx.x;
  const int t   = threadIdx.x;

  if (bid < 6144) {
    const int u   = bid * 4 + (t >> 6);   // (mt, ks) unit, u < 24576
    const int mt  = u / 24;
    const int ks  = u - mt * 24;
    const int lam = t & 63;
    const int ml  = lam & 15;
    const int q   = lam >> 4;
    const float* src = x + (size_t)(mt * 16 + ml) * EMBED + ks * 32 + q * 8;
    const float4 a0 = *(const float4*)src;
    const float4 a1 = *(const float4*)(src + 4);
    u16x8 hv, lv;
    hl16 s;
    s = splitHW(a0.x); hv[0] = s.h; lv[0] = s.l;
    s = splitHW(a0.y); hv[1] = s.h; lv[1] = s.l;
    s = splitHW(a0.z); hv[2] = s.h; lv[2] = s.l;
    s = splitHW(a0.w); hv[3] = s.h; lv[3] = s.l;
    s = splitHW(a1.x); hv[4] = s.h; lv[4] = s.l;
    s = splitHW(a1.y); hv[5] = s.h; lv[5] = s.l;
    s = splitHW(a1.z); hv[6] = s.h; lv[6] = s.l;
    s = splitHW(a1.w); hv[7] = s.h; lv[7] = s.l;
    unsigned short* dst = Xt + (size_t)(mt * 24 + ks) * 1024 + lam * 8;
    *(u16x8*)dst         = hv;   // plane h
    *(u16x8*)(dst + 512) = lv;   // plane l
    return;
  }

  // ---- W transpose/split path ----
  const int b   = bid - 6144;           // 0..71
  const int mat = b / 24;               // 0=Wq 1=Wk 2=Wv
  const int ks  = b - mat * 24;
  const float* W = (mat == 0) ? Wq : (mat == 1) ? Wk : Wv;

  const float4* src = (const float4*)(W + ks * 2048);
  ((float4*)tile)[t]       = src[t];
  ((float4*)tile)[t + 256] = src[t + 256];
  __syncthreads();

  const int q    = t >> 6;              // k-oct 0..3
  const int nloc = t & 63;
  u16x8 hv, lv;
#pragma unroll
  for (int j = 0; j < 8; ++j) {
    hl16 s = split2(tile[(q * 8 + j) * 64 + nloc]);
    hv[j] = s.h; lv[j] = s.l;
  }

  const int n   = mat * 64 + nloc;
  const int nqb = n / 48;
  const int col = n - nqb * 48;
  unsigned short* dst = Wt + (size_t)nqb * 73728 + (size_t)ks * 3072 + q * 384 + col * 8;
  *(u16x8*)dst          = hv;   // p=0
  *(u16x8*)(dst + 1536) = lv;   // p=1

  if (b == 0) Vsum[t] = 0.f;    // 256 threads = NB*64 slots
}

// ---------------------------------------------------------------------------
// MFMA GEMM: C[16384][192] = Xsplit @ Wsplit + bias (3-pass split-bf16).
// 256 blocks (1/CU) x 512 threads (8 waves). Block = 256 rows x 48 cols x
// FULL 768 k (no k-split -> no merge/atomics). B slice (144 KiB) staged to
// LDS once (global_load_lds, single barrier), then free-running k-loop:
// per k32-step per wave: 4 coalesced 1-KiB A-loads (Xt, fragment-ordered),
// 6 ds_read_b128 (2-way bank alias = free), 18 MFMA 16x16x32. No in-loop
// cvt, no barriers. bid->(mc,nqb) maps the 4 n-blocks of an m-chunk to one
// XCD for Xt L2 reuse. Fused bias + Vsum epilogue.
// ---------------------------------------------------------------------------
__device__ inline void gload_lds16(const unsigned short* g, unsigned short* l) {
  __builtin_amdgcn_global_load_lds(
      (const __attribute__((address_space(1))) unsigned int*)(g),
      (__attribute__((address_space(3))) unsigned int*)(l),
      16, 0, 0);
}

#define MF(A, B, ACC) ACC = __builtin_amdgcn_mfma_f32_16x16x32_bf16(A, B, ACC, 0, 0, 0)

__global__ __launch_bounds__(512, 2) void qkv_mfma(const unsigned short* __restrict__ Xt,
                                                   const unsigned short* __restrict__ Wtu,
                                                   const float* __restrict__ bq,
                                                   const float* __restrict__ bk,
                                                   const float* __restrict__ bv,
                                                   float* __restrict__ C,
                                                   float* __restrict__ Vsum) {
  extern __shared__ unsigned short lds[];   // 73728 shorts = 147456 B

  const int tid  = threadIdx.x;
  const int lane = tid & 63;
  const int wm   = tid >> 6;            // wave 0..7 : 32-row slice
  const int nl   = lane & 15;
  const int q    = lane >> 4;           // k-oct
  const int bid  = blockIdx.x;
  const int mc   = (bid & 7) * 8 + (bid >> 5);   // m-chunk 0..63 (XCD-grouped)
  const int nqb  = (bid >> 3) & 3;               // n-block 0..3
  const int nbase = nqb * 48;
  const int r0w  = mc * 256 + wm * 32;
  const int mt0  = mc * 16 + wm * 2;    // first 16-row tile index

  // ---- stage B slice (verbatim 144 KiB) ----
  {
    const unsigned short* g = Wtu + (size_t)nqb * 73728 + tid * 8;
    unsigned short* l = lds + tid * 8;
#pragma unroll
    for (int i = 0; i < 18; ++i)
      gload_lds16(g + i * 4096, l + i * 4096);
  }

  f32x4 acc00 = {0.f,0.f,0.f,0.f}, acc01 = {0.f,0.f,0.f,0.f}, acc02 = {0.f,0.f,0.f,0.f};
  f32x4 acc10 = {0.f,0.f,0.f,0.f}, acc11 = {0.f,0.f,0.f,0.f}, acc12 = {0.f,0.f,0.f,0.f};

  // A fragment pointers (bf16x8 units): frag(ks,p) = XA[ks*128 + p*64]
  const bf16x8* XA0 = (const bf16x8*)Xt + (size_t)mt0 * 3072 + lane;
  const bf16x8* XA1 = XA0 + 3072;

  // prologue A(ks=0) — independent of LDS staging
  bf16x8 ah0 = XA0[0], al0 = XA0[64];
  bf16x8 ah1 = XA1[0], al1 = XA1[64];

  __syncthreads();   // B staged (barrier drains global_load_lds)

  // B fragment base (bf16x8 units): frag(ks,p,nt) = LB[ks*384 + p*192 + nt*16]
  const bf16x8* LB = (const bf16x8*)lds + q * 48 + nl;

  for (int ks = 0; ks < 24; ++ks) {
    const int o = ks * 384;
    bf16x8 bh0 = LB[o],       bh1 = LB[o + 16],  bh2 = LB[o + 32];
    bf16x8 bl0 = LB[o + 192], bl1 = LB[o + 208], bl2 = LB[o + 224];
    bf16x8 nh0, nl0, nh1, nl1;
    if (ks < 23) {                       // prefetch next A (coalesced, L2/L3)
      nh0 = XA0[(ks + 1) * 128]; nl0 = XA0[(ks + 1) * 128 + 64];
      nh1 = XA1[(ks + 1) * 128]; nl1 = XA1[(ks + 1) * 128 + 64];
    }
    MF(ah0, bh0, acc00); MF(ah1, bh0, acc10);
    MF(ah0, bh1, acc01); MF(ah1, bh1, acc11);
    MF(ah0, bh2, acc02); MF(ah1, bh2, acc12);
    MF(ah0, bl0, acc00); MF(ah1, bl0, acc10);
    MF(ah0, bl1, acc01); MF(ah1, bl1, acc11);
    MF(ah0, bl2, acc02); MF(ah1, bl2, acc12);
    MF(al0, bh0, acc00); MF(al1, bh0, acc10);
    MF(al0, bh1, acc01); MF(al1, bh1, acc11);
    MF(al0, bh2, acc02); MF(al1, bh2, acc12);
    ah0 = nh0; al0 = nl0; ah1 = nh1; al1 = nl1;
  }

  // ---- epilogue: bias + plain stores. C/D: col = nl, row = q*4 + reg ----
#define EPI(MI, NT, ACC) do {                                               \
    const int col = nbase + (NT) * 16 + nl;                                 \
    const float bias = (col < 64) ? bq[col]                                 \
                     : (col < 128) ? bk[col - 64] : bv[col - 128];          \
    const int row = r0w + (MI) * 16 + q * 4;                                \
    C[(size_t)(row + 0) * CN + col] = ACC[0] + bias;                        \
    C[(size_t)(row + 1) * CN + col] = ACC[1] + bias;                        \
    C[(size_t)(row + 2) * CN + col] = ACC[2] + bias;                        \
    C[(size_t)(row + 3) * CN + col] = ACC[3] + bias;                        \
  } while (0)

  EPI(0, 0, acc00); EPI(0, 1, acc01); EPI(0, 2, acc02);
  EPI(1, 0, acc10); EPI(1, 1, acc11); EPI(1, 2, acc12);

  // ---- fused Vsum partials (V cols >= 128): per lane 8 rows (+8x bias),
  // shfl over 4 q-groups -> 32 rows of this wave, one atomic per col ----
#define VS(NT, A0, A1) do {                                                 \
    const int col = nbase + (NT) * 16 + nl;                                 \
    if (col >= 128) {                                                       \
      float s = A0[0] + A0[1] + A0[2] + A0[3]                               \
              + A1[0] + A1[1] + A1[2] + A1[3] + 8.f * bv[col - 128];        \
      s += __shfl_xor(s, 16, 64);                                           \
      s += __shfl_xor(s, 32, 64);                                           \
      if (q == 0) atomicAdd(&Vsum[(r0w >> 12) * 64 + (col - 128)], s);      \
    }                                                                       \
  } while (0)

  VS(0, acc00, acc10); VS(1, acc01, acc11); VS(2, acc02, acc12);
}

// ---------------------------------------------------------------------------
// Per-row scores + softmax-with-zero-background + V combine (faithful quirk).
// ---------------------------------------------------------------------------
__global__ __launch_bounds__(256) void attn_kernel(const float* __restrict__ C,
                                                   const float* __restrict__ Vsum,
                                                   float* __restrict__ out) {
  const int t    = threadIdx.x;
  const int lane = t & 63;
  const int wave = t >> 6;
  const int r = blockIdx.x * 4 + wave;
  const int b = r >> 12;
  const int i = r & (NTOK - 1);

  const float q  = C[(size_t)r * CN + lane];
  const float kc = C[(size_t)r * CN + 64 + lane];
  float km = 0.f, kp = 0.f;
  if (i > 0)        km = C[(size_t)(r - 1) * CN + 64 + lane];
  if (i < NTOK - 1) kp = C[(size_t)(r + 1) * CN + 64 + lane];

  float p0 = q * km, p1 = q * kc, p2 = q * kp;
#pragma unroll
  for (int off = 32; off > 0; off >>= 1) {
    p0 += __shfl_xor(p0, off, 64);
    p1 += __shfl_xor(p1, off, 64);
    p2 += __shfl_xor(p2, off, 64);
  }

  const float s0 = (i > 0) ? p0 : 0.f;
  const float s1 = p1;
  const float s2 = (i < NTOK - 1) ? p2 : 0.f;
  const float m  = fmaxf(fmaxf(s0, s1), fmaxf(s2, 0.f));
  const float e0 = expf(s0 - m);
  const float e1 = expf(s1 - m);
  const float e2 = expf(s2 - m);
  const float ez = expf(-m);
  const float Z  = e0 + e1 + e2 + (float)(NTOK - 3) * ez;

  const size_t vb = ((size_t)b * NTOK) * CN + 128;
  const float v0 = C[vb + lane];
  const float v1 = C[vb + CN + lane];
  const float v2 = C[vb + 2 * (size_t)CN + lane];
  const float vs = Vsum[b * 64 + lane];

  out[(size_t)r * 64 + lane] =
      (e0 * v0 + e1 * v1 + e2 * v2 + ez * (vs - v0 - v1 - v2)) / Z;
}

// ---------------------------------------------------------------------------
extern "C" void kernel_launch(void* const* d_in, const int* in_sizes, int n_in,
                              void* d_out, int out_size, void* d_ws, size_t ws_size,
                              hipStream_t stream) {
  const float* x  = (const float*)d_in[0];
  const float* Wq = (const float*)d_in[1];
  const float* bq = (const float*)d_in[2];
  const float* Wk = (const float*)d_in[3];
  const float* bk = (const float*)d_in[4];
  const float* Wv = (const float*)d_in[5];
  const float* bv = (const float*)d_in[6];
  float* out = (float*)d_out;

  float* C    = (float*)d_ws;                              // 16384 x 192 fp32 (12 MiB)
  float* Vsum = C + (size_t)ROWS * CN;                     // 256 floats
  unsigned short* Wt = (unsigned short*)(Vsum + NB * 64);  // 4 x 73728 shorts (576 KiB)
  unsigned short* Xt = Wt + 4 * 73728;                     // 25,165,824 shorts (48 MiB)

  prep<<<6216, 256, 0, stream>>>(x, Wq, Wk, Wv, Wt, Xt, Vsum);
  qkv_mfma<<<256, 512, 147456, stream>>>(Xt, Wt, bq, bk, bv, C, Vsum);
  attn_kernel<<<ROWS / 4, 256, 0, stream>>>(C, Vsum, out);
}

// Round 9
// 126.580 us; speedup vs baseline: 1.2549x; 1.0074x over previous
//
#include <hip/hip_runtime.h>
#include <hip/hip_bf16.h>
#include <math.h>

#define EMBED 768
#define NTOK  4096
#define NB    4
#define ROWS  16384          // 4 * 4096
#define CN    192            // Q(64)|K(64)|V(64)

typedef __attribute__((ext_vector_type(8))) short bf16x8;          // 8 bf16 = 4 VGPR
typedef __attribute__((ext_vector_type(8))) unsigned short u16x8;  // store vector
typedef __attribute__((ext_vector_type(4))) float f32x4;           // MFMA acc

struct hl16 { unsigned short h, l; };

// RNE split f = h + l (both planes RNE, tie-parity exact): W path.
__device__ inline hl16 split2(float f) {
  hl16 r;
  union { float f; unsigned u; } a; a.f = f;
  unsigned rr = (a.u + 0x7FFFu + ((a.u >> 16) & 1u)) & 0xFFFF0000u;
  r.h = (unsigned short)(rr >> 16);
  union { unsigned u; float f; } hf; hf.u = rr;
  union { float f; unsigned u; } b; b.f = f - hf.f;
  r.l = (unsigned short)((b.u + 0x7FFFu + ((b.u >> 16) & 1u)) >> 16);
  return r;
}

// HW RNE split (v_cvt path): X path — same rounding as rounds 2-8.
__device__ inline hl16 splitHW(float f) {
  hl16 r;
  __hip_bfloat16 hb = __float2bfloat16(f);
  float hf = __bfloat162float(hb);
  __hip_bfloat16 lb = __float2bfloat16(f - hf);
  r.h = __builtin_bit_cast(unsigned short, hb);
  r.l = __builtin_bit_cast(unsigned short, lb);
  return r;
}

// ---------------------------------------------------------------------------
// prep: (a) Xt — x pre-split to bf16 h/l planes in MFMA-A-fragment order:
//   Xt[(mt*24 + ks)*1024 + p*512 + lane*8 + j], lane = q*16 + ml,
//   element = x[row = mt*16 + ml][k = ks*32 + q*8 + j].
//   => a wave's A-fragment load in qkv is ONE contiguous 1 KiB read.
// (b) Wt — W split to h/l planes, n-block-major so qkv's 144-KiB LDS stage
//   is a verbatim linear copy:
//   Wt[nqb*73728 + ks*3072 + p*1536 + q*384 + col*8 + j], n = nqb*48 + col.
// (c) zeroes Vsum.
// Blocks [0,6144): Xt (4 units of 64 lanes each). Blocks [6144,6216): Wt.
// ---------------------------------------------------------------------------
__global__ __launch_bounds__(256) void prep(const float* __restrict__ x,
                                            const float* __restrict__ Wq,
                                            const float* __restrict__ Wk,
                                            const float* __restrict__ Wv,
                                            unsigned short* __restrict__ Wt,
                                            unsigned short* __restrict__ Xt,
                                            float* __restrict__ Vsum) {
  __shared__ float tile[32 * 64];
  const int bid = blockIdx.x;
  const int t   = threadIdx.x;

  if (bid < 6144) {
    const int u   = bid * 4 + (t >> 6);   // (mt, ks) unit, u < 24576
    const int mt  = u / 24;
    const int ks  = u - mt * 24;
    const int lam = t & 63;
    const int ml  = lam & 15;
    const int q   = lam >> 4;
    const float* src = x + (size_t)(mt * 16 + ml) * EMBED + ks * 32 + q * 8;
    const float4 a0 = *(const float4*)src;
    const float4 a1 = *(const float4*)(src + 4);
    u16x8 hv, lv;
    hl16 s;
    s = splitHW(a0.x); hv[0] = s.h; lv[0] = s.l;
    s = splitHW(a0.y); hv[1] = s.h; lv[1] = s.l;
    s = splitHW(a0.z); hv[2] = s.h; lv[2] = s.l;
    s = splitHW(a0.w); hv[3] = s.h; lv[3] = s.l;
    s = splitHW(a1.x); hv[4] = s.h; lv[4] = s.l;
    s = splitHW(a1.y); hv[5] = s.h; lv[5] = s.l;
    s = splitHW(a1.z); hv[6] = s.h; lv[6] = s.l;
    s = splitHW(a1.w); hv[7] = s.h; lv[7] = s.l;
    unsigned short* dst = Xt + (size_t)(mt * 24 + ks) * 1024 + lam * 8;
    *(u16x8*)dst         = hv;   // plane h
    *(u16x8*)(dst + 512) = lv;   // plane l
    return;
  }

  // ---- W transpose/split path ----
  const int b   = bid - 6144;           // 0..71
  const int mat = b / 24;               // 0=Wq 1=Wk 2=Wv
  const int ks  = b - mat * 24;
  const float* W = (mat == 0) ? Wq : (mat == 1) ? Wk : Wv;

  const float4* src = (const float4*)(W + ks * 2048);
  ((float4*)tile)[t]       = src[t];
  ((float4*)tile)[t + 256] = src[t + 256];
  __syncthreads();

  const int q    = t >> 6;              // k-oct 0..3
  const int nloc = t & 63;
  u16x8 hv, lv;
#pragma unroll
  for (int j = 0; j < 8; ++j) {
    hl16 s = split2(tile[(q * 8 + j) * 64 + nloc]);
    hv[j] = s.h; lv[j] = s.l;
  }

  const int n   = mat * 64 + nloc;
  const int nqb = n / 48;
  const int col = n - nqb * 48;
  unsigned short* dst = Wt + (size_t)nqb * 73728 + (size_t)ks * 3072 + q * 384 + col * 8;
  *(u16x8*)dst          = hv;   // p=0
  *(u16x8*)(dst + 1536) = lv;   // p=1

  if (b == 0) Vsum[t] = 0.f;    // 256 threads = NB*64 slots
}

// ---------------------------------------------------------------------------
// MFMA GEMM: C[16384][192] = Xsplit @ Wsplit + bias (3-pass split-bf16).
// 256 blocks x 1024 threads = 16 waves: 8 m-slices x 2 K-HALVES (within-block
// k-split -> 4 waves/SIMD, 12-step loop/wave; no atomics). Block = 256 rows
// x 48 cols. B slice (144 KiB) staged to LDS once (global_load_lds, one
// barrier). Free-running k-loop: 4 coalesced 1-KiB A-loads (Xt, fragment-
// ordered, 1-deep prefetch) + 6 ds_read_b128 + 18 MFMA per step. K-halves
// merged via LDS (B region reused AFTER the loop; 2 barriers, both outside
// the hot loop). kh=0 waves add partials, apply bias, store C, fuse Vsum.
// ---------------------------------------------------------------------------
__device__ inline void gload_lds16(const unsigned short* g, unsigned short* l) {
  __builtin_amdgcn_global_load_lds(
      (const __attribute__((address_space(1))) unsigned int*)(g),
      (__attribute__((address_space(3))) unsigned int*)(l),
      16, 0, 0);
}

#define MF(A, B, ACC) ACC = __builtin_amdgcn_mfma_f32_16x16x32_bf16(A, B, ACC, 0, 0, 0)

__global__ __launch_bounds__(1024, 4) void qkv_mfma(const unsigned short* __restrict__ Xt,
                                                    const unsigned short* __restrict__ Wtu,
                                                    const float* __restrict__ bq,
                                                    const float* __restrict__ bk,
                                                    const float* __restrict__ bv,
                                                    float* __restrict__ C,
                                                    float* __restrict__ Vsum) {
  extern __shared__ unsigned short lds[];   // 73728 shorts = 147456 B

  const int tid  = threadIdx.x;
  const int lane = tid & 63;
  const int wid  = tid >> 6;            // 0..15
  const int wm   = wid & 7;             // m-slice (32 rows)
  const int kh   = wid >> 3;            // k-half 0..1
  const int nl   = lane & 15;
  const int q    = lane >> 4;           // k-oct
  const int bid  = blockIdx.x;
  const int mc   = (bid & 7) * 8 + (bid >> 5);   // m-chunk 0..63 (XCD-grouped)
  const int nqb  = (bid >> 3) & 3;               // n-block 0..3
  const int nbase = nqb * 48;
  const int r0w  = mc * 256 + wm * 32;
  const int mt0  = mc * 16 + wm * 2;    // first 16-row tile index

  // ---- stage B slice (verbatim 144 KiB; 1024 threads x 9 x 16 B) ----
  {
    const unsigned short* g = Wtu + (size_t)nqb * 73728 + tid * 8;
    unsigned short* l = lds + tid * 8;
#pragma unroll
    for (int i = 0; i < 9; ++i)
      gload_lds16(g + i * 8192, l + i * 8192);
  }

  f32x4 acc00 = {0.f,0.f,0.f,0.f}, acc01 = {0.f,0.f,0.f,0.f}, acc02 = {0.f,0.f,0.f,0.f};
  f32x4 acc10 = {0.f,0.f,0.f,0.f}, acc11 = {0.f,0.f,0.f,0.f}, acc12 = {0.f,0.f,0.f,0.f};

  // A fragment pointers (bf16x8 units): frag(s,p) = XA[s*128 + p*64]
  const bf16x8* XA0 = (const bf16x8*)Xt + ((size_t)mt0 * 24 + kh * 12) * 128 + lane;
  const bf16x8* XA1 = XA0 + 24 * 128;

  // prologue A(s=0) — independent of LDS staging
  bf16x8 ah0 = XA0[0], al0 = XA0[64];
  bf16x8 ah1 = XA1[0], al1 = XA1[64];

  __syncthreads();   // B staged (barrier drains global_load_lds)

  // B fragment base (bf16x8 units): frag(s,p,nt) = LB[s*384 + p*192 + nt*16]
  const bf16x8* LB = (const bf16x8*)lds + kh * 12 * 384 + q * 48 + nl;

  for (int s = 0; s < 12; ++s) {
    const int o = s * 384;
    bf16x8 bh0 = LB[o],       bh1 = LB[o + 16],  bh2 = LB[o + 32];
    bf16x8 bl0 = LB[o + 192], bl1 = LB[o + 208], bl2 = LB[o + 224];
    bf16x8 nh0, nl0, nh1, nl1;
    if (s < 11) {                        // prefetch next A (coalesced, L2/L3)
      nh0 = XA0[(s + 1) * 128]; nl0 = XA0[(s + 1) * 128 + 64];
      nh1 = XA1[(s + 1) * 128]; nl1 = XA1[(s + 1) * 128 + 64];
    }
    MF(ah0, bh0, acc00); MF(ah1, bh0, acc10);
    MF(ah0, bh1, acc01); MF(ah1, bh1, acc11);
    MF(ah0, bh2, acc02); MF(ah1, bh2, acc12);
    MF(ah0, bl0, acc00); MF(ah1, bl0, acc10);
    MF(ah0, bl1, acc01); MF(ah1, bl1, acc11);
    MF(ah0, bl2, acc02); MF(ah1, bl2, acc12);
    MF(al0, bh0, acc00); MF(al1, bh0, acc10);
    MF(al0, bh1, acc01); MF(al1, bh1, acc11);
    MF(al0, bh2, acc02); MF(al1, bh2, acc12);
    ah0 = nh0; al0 = nl0; ah1 = nh1; al1 = nl1;
  }

  // ---- K-half merge through LDS (re-using the B region) ----
  float* fl = (float*)lds;              // 256 rows x 48 cols fp32 = 48 KiB
  __syncthreads();                      // everyone done reading B

#define PST(MI, NT, ACC) do {                                               \
    const int rb = wm * 32 + (MI) * 16 + q * 4;                             \
    const int c  = (NT) * 16 + nl;                                          \
    fl[(rb + 0) * 48 + c] = ACC[0];                                         \
    fl[(rb + 1) * 48 + c] = ACC[1];                                         \
    fl[(rb + 2) * 48 + c] = ACC[2];                                         \
    fl[(rb + 3) * 48 + c] = ACC[3];                                         \
  } while (0)

  if (kh == 1) {
    PST(0, 0, acc00); PST(0, 1, acc01); PST(0, 2, acc02);
    PST(1, 0, acc10); PST(1, 1, acc11); PST(1, 2, acc12);
  }
  __syncthreads();
  if (kh == 1) return;

#define ADDP(MI, NT, ACC) do {                                              \
    const int rb = wm * 32 + (MI) * 16 + q * 4;                             \
    const int c  = (NT) * 16 + nl;                                          \
    ACC[0] += fl[(rb + 0) * 48 + c];                                        \
    ACC[1] += fl[(rb + 1) * 48 + c];                                        \
    ACC[2] += fl[(rb + 2) * 48 + c];                                        \
    ACC[3] += fl[(rb + 3) * 48 + c];                                        \
  } while (0)

  ADDP(0, 0, acc00); ADDP(0, 1, acc01); ADDP(0, 2, acc02);
  ADDP(1, 0, acc10); ADDP(1, 1, acc11); ADDP(1, 2, acc12);

  // ---- epilogue: bias + plain stores. C/D: col = nl, row = q*4 + reg ----
#define EPI(MI, NT, ACC) do {                                               \
    const int col = nbase + (NT) * 16 + nl;                                 \
    const float bias = (col < 64) ? bq[col]                                 \
                     : (col < 128) ? bk[col - 64] : bv[col - 128];          \
    const int row = r0w + (MI) * 16 + q * 4;                                \
    C[(size_t)(row + 0) * CN + col] = ACC[0] + bias;                        \
    C[(size_t)(row + 1) * CN + col] = ACC[1] + bias;                        \
    C[(size_t)(row + 2) * CN + col] = ACC[2] + bias;                        \
    C[(size_t)(row + 3) * CN + col] = ACC[3] + bias;                        \
  } while (0)

  EPI(0, 0, acc00); EPI(0, 1, acc01); EPI(0, 2, acc02);
  EPI(1, 0, acc10); EPI(1, 1, acc11); EPI(1, 2, acc12);

  // ---- fused Vsum partials (V cols >= 128): per lane 8 rows (+8x bias),
  // shfl over 4 q-groups -> 32 rows of this wave, one atomic per col ----
#define VS(NT, A0, A1) do {                                                 \
    const int col = nbase + (NT) * 16 + nl;                                 \
    if (col >= 128) {                                                       \
      float sv = A0[0] + A0[1] + A0[2] + A0[3]                              \
               + A1[0] + A1[1] + A1[2] + A1[3] + 8.f * bv[col - 128];       \
      sv += __shfl_xor(sv, 16, 64);                                         \
      sv += __shfl_xor(sv, 32, 64);                                         \
      if (q == 0) atomicAdd(&Vsum[(r0w >> 12) * 64 + (col - 128)], sv);     \
    }                                                                       \
  } while (0)

  VS(0, acc00, acc10); VS(1, acc01, acc11); VS(2, acc02, acc12);
}

// ---------------------------------------------------------------------------
// Per-row scores + softmax-with-zero-background + V combine (faithful quirk).
// ---------------------------------------------------------------------------
__global__ __launch_bounds__(256) void attn_kernel(const float* __restrict__ C,
                                                   const float* __restrict__ Vsum,
                                                   float* __restrict__ out) {
  const int t    = threadIdx.x;
  const int lane = t & 63;
  const int wave = t >> 6;
  const int r = blockIdx.x * 4 + wave;
  const int b = r >> 12;
  const int i = r & (NTOK - 1);

  const float q  = C[(size_t)r * CN + lane];
  const float kc = C[(size_t)r * CN + 64 + lane];
  float km = 0.f, kp = 0.f;
  if (i > 0)        km = C[(size_t)(r - 1) * CN + 64 + lane];
  if (i < NTOK - 1) kp = C[(size_t)(r + 1) * CN + 64 + lane];

  float p0 = q * km, p1 = q * kc, p2 = q * kp;
#pragma unroll
  for (int off = 32; off > 0; off >>= 1) {
    p0 += __shfl_xor(p0, off, 64);
    p1 += __shfl_xor(p1, off, 64);
    p2 += __shfl_xor(p2, off, 64);
  }

  const float s0 = (i > 0) ? p0 : 0.f;
  const float s1 = p1;
  const float s2 = (i < NTOK - 1) ? p2 : 0.f;
  const float m  = fmaxf(fmaxf(s0, s1), fmaxf(s2, 0.f));
  const float e0 = expf(s0 - m);
  const float e1 = expf(s1 - m);
  const float e2 = expf(s2 - m);
  const float ez = expf(-m);
  const float Z  = e0 + e1 + e2 + (float)(NTOK - 3) * ez;

  const size_t vb = ((size_t)b * NTOK) * CN + 128;
  const float v0 = C[vb + lane];
  const float v1 = C[vb + CN + lane];
  const float v2 = C[vb + 2 * (size_t)CN + lane];
  const float vs = Vsum[b * 64 + lane];

  out[(size_t)r * 64 + lane] =
      (e0 * v0 + e1 * v1 + e2 * v2 + ez * (vs - v0 - v1 - v2)) / Z;
}

// ---------------------------------------------------------------------------
extern "C" void kernel_launch(void* const* d_in, const int* in_sizes, int n_in,
                              void* d_out, int out_size, void* d_ws, size_t ws_size,
                              hipStream_t stream) {
  const float* x  = (const float*)d_in[0];
  const float* Wq = (const float*)d_in[1];
  const float* bq = (const float*)d_in[2];
  const float* Wk = (const float*)d_in[3];
  const float* bk = (const float*)d_in[4];
  const float* Wv = (const float*)d_in[5];
  const float* bv = (const float*)d_in[6];
  float* out = (float*)d_out;

  float* C    = (float*)d_ws;                              // 16384 x 192 fp32 (12 MiB)
  float* Vsum = C + (size_t)ROWS * CN;                     // 256 floats
  unsigned short* Wt = (unsigned short*)(Vsum + NB * 64);  // 4 x 73728 shorts (576 KiB)
  unsigned short* Xt = Wt + 4 * 73728;                     // 24 M shorts (48 MiB)

  prep<<<6216, 256, 0, stream>>>(x, Wq, Wk, Wv, Wt, Xt, Vsum);
  qkv_mfma<<<256, 1024, 147456, stream>>>(Xt, Wt, bq, bk, bv, C, Vsum);
  attn_kernel<<<ROWS / 4, 256, 0, stream>>>(C, Vsum, out);
}